// Round 4
// baseline (765.966 us; speedup 1.0000x reference)
//
#include <hip/hip_runtime.h>
#include <hip/hip_bf16.h>
#include <math.h>

#define N_NODES 100000
#define N_EDGES 1600000
#define F_IN 128
#define F_EDGE 16
#define HC 128   // HEADS*C = 4*32
#define NEG 0.2f
#define NB_SCAN 98   // ceil(N_NODES/1024)

typedef unsigned int uint;

__device__ __forceinline__ float bf_lo(uint u) { return __uint_as_float(u << 16); }
__device__ __forceinline__ float bf_hi(uint u) { return __uint_as_float(u & 0xffff0000u); }
__device__ __forceinline__ uint f2bfbits(float f) {
    union { __hip_bfloat16 h; unsigned short u; } cv;
    cv.h = __float2bfloat16(f);
    return (uint)cv.u;
}
__device__ __forceinline__ uint pack_bf2(float lo, float hi) {
    return f2bfbits(lo) | (f2bfbits(hi) << 16);
}

#if defined(__has_builtin)
#if __has_builtin(__builtin_amdgcn_fdot2_f32_bf16)
#define HAVE_DOT2_BF16 1
#endif
#endif

#ifdef HAVE_DOT2_BF16
typedef __attribute__((ext_vector_type(2))) __bf16 bf16x2_t;
__device__ __forceinline__ float dot2bf(uint a, uint b, float c) {
    return __builtin_amdgcn_fdot2_f32_bf16(
        __builtin_bit_cast(bf16x2_t, a), __builtin_bit_cast(bf16x2_t, b), c, false);
}
#else
__device__ __forceinline__ float dot2bf(uint a, uint b, float c) {
    return fmaf(bf_lo(a), bf_lo(b), fmaf(bf_hi(a), bf_hi(b), c));
}
#endif

// ---------------------------------------------------------------------------
// Projection with bf16 LDS tiles + dot2: xl = bf16(x@Wl^T+bl), xr = f32(x@Wr^T+br)
// LDS 32KB -> 4 blocks/CU. 64x64 tile, 4x4 per thread.
// ---------------------------------------------------------------------------
__global__ __launch_bounds__(256) void proj_kernel(
    const float* __restrict__ x,
    const float* __restrict__ Wl, const float* __restrict__ bl,
    const float* __restrict__ Wr, const float* __restrict__ br,
    unsigned short* __restrict__ xlb, float* __restrict__ xr)
{
    __shared__ uint2 xs[64 * 32];   // 16KB: row r, uint2 slot u (4 bf16 each)
    __shared__ uint2 ws[64 * 32];   // 16KB

    int bx = blockIdx.x;
    int rb = bx >> 2;
    int cb = bx & 3;
    int row0 = rb * 64;
    int col0 = (cb & 1) * 64;
    const float* W    = (cb < 2) ? Wl : Wr;
    const float* bias = (cb < 2) ? bl : br;

    int tid = threadIdx.x;

    #pragma unroll
    for (int i = 0; i < 8; ++i) {
        int f  = tid + 256 * i;
        int r  = f >> 5;
        int u  = f & 31;
        int gr = row0 + r;
        float4 v = make_float4(0.f, 0.f, 0.f, 0.f);
        if (gr < N_NODES) v = ((const float4*)(x + (size_t)gr * F_IN))[u];
        uint2 pv; pv.x = pack_bf2(v.x, v.y); pv.y = pack_bf2(v.z, v.w);
        xs[r * 32 + (u ^ (r & 31))] = pv;
    }
    #pragma unroll
    for (int i = 0; i < 8; ++i) {
        int f  = tid + 256 * i;
        int r  = f >> 5;
        int u  = f & 31;
        float4 v = ((const float4*)(W + (size_t)(col0 + r) * F_IN))[u];
        uint2 pv; pv.x = pack_bf2(v.x, v.y); pv.y = pack_bf2(v.z, v.w);
        ws[r * 32 + (u ^ (r & 31))] = pv;
    }
    __syncthreads();

    int tx = tid & 15, ty = tid >> 4;
    float acc[4][4];
    #pragma unroll
    for (int i = 0; i < 4; ++i)
        #pragma unroll
        for (int j = 0; j < 4; ++j) acc[i][j] = 0.f;

    for (int u = 0; u < 32; ++u) {
        uint2 a[4], b[4];
        #pragma unroll
        for (int i = 0; i < 4; ++i) {
            int r = ty + 16 * i;
            a[i] = xs[r * 32 + (u ^ (r & 31))];
        }
        #pragma unroll
        for (int j = 0; j < 4; ++j) {
            int r = tx + 16 * j;
            b[j] = ws[r * 32 + (u ^ (r & 31))];
        }
        #pragma unroll
        for (int i = 0; i < 4; ++i)
            #pragma unroll
            for (int j = 0; j < 4; ++j) {
                acc[i][j] = dot2bf(a[i].x, b[j].x, acc[i][j]);
                acc[i][j] = dot2bf(a[i].y, b[j].y, acc[i][j]);
            }
    }

    #pragma unroll
    for (int i = 0; i < 4; ++i) {
        int gr = row0 + ty + 16 * i;
        if (gr >= N_NODES) continue;
        #pragma unroll
        for (int j = 0; j < 4; ++j) {
            int c = col0 + tx + 16 * j;
            float v = acc[i][j] + bias[c];
            if (cb < 2) xlb[(size_t)gr * HC + c] = (unsigned short)f2bfbits(v);
            else        xr[(size_t)gr * HC + c]  = v;
        }
    }
}

// ---------------------------------------------------------------------------
// Fused: edge_attr f32 -> packed bf16 (edge order) + degree count
__global__ void ea2bf_count_kernel(
    const float* __restrict__ edge_attr, const int* __restrict__ dst,
    uint4* __restrict__ ea_bf, int* __restrict__ deg)
{
    int e = blockIdx.x * blockDim.x + threadIdx.x;
    if (e < N_EDGES) {
        const float4* ep = (const float4*)(edge_attr + (size_t)e * F_EDGE);
        float4 t0 = ep[0], t1 = ep[1], t2 = ep[2], t3 = ep[3];
        uint4 a, b;
        a.x = pack_bf2(t0.x, t0.y);  a.y = pack_bf2(t0.z, t0.w);
        a.z = pack_bf2(t1.x, t1.y);  a.w = pack_bf2(t1.z, t1.w);
        b.x = pack_bf2(t2.x, t2.y);  b.y = pack_bf2(t2.z, t2.w);
        b.z = pack_bf2(t3.x, t3.y);  b.w = pack_bf2(t3.z, t3.w);
        ea_bf[2 * (size_t)e]     = a;
        ea_bf[2 * (size_t)e + 1] = b;
        atomicAdd(&deg[dst[e]], 1);
    }
}

// 3-phase scan
__global__ __launch_bounds__(1024) void scan1_kernel(
    const int* __restrict__ deg, int* __restrict__ row_start, int* __restrict__ bsum)
{
    __shared__ int sm[1024];
    int t = threadIdx.x;
    int i = blockIdx.x * 1024 + t;
    int v = (i < N_NODES) ? deg[i] : 0;
    sm[t] = v;
    __syncthreads();
    for (int off = 1; off < 1024; off <<= 1) {
        int o = (t >= off) ? sm[t - off] : 0;
        __syncthreads();
        sm[t] += o;
        __syncthreads();
    }
    if (i < N_NODES) row_start[i] = sm[t] - v;
    if (t == 1023) bsum[blockIdx.x] = sm[1023];
}

__global__ __launch_bounds__(128) void scan2_kernel(
    const int* __restrict__ bsum, int* __restrict__ boff)
{
    __shared__ int sm[128];
    int t = threadIdx.x;
    int v = (t < NB_SCAN) ? bsum[t] : 0;
    sm[t] = v;
    __syncthreads();
    for (int off = 1; off < 128; off <<= 1) {
        int o = (t >= off) ? sm[t - off] : 0;
        __syncthreads();
        sm[t] += o;
        __syncthreads();
    }
    if (t < NB_SCAN) boff[t] = sm[t] - v;
}

__global__ __launch_bounds__(1024) void scan3_kernel(
    int* __restrict__ row_start, const int* __restrict__ boff, int* __restrict__ cursor)
{
    int i = blockIdx.x * 1024 + threadIdx.x;
    if (i < N_NODES) {
        int r = row_start[i] + boff[blockIdx.x];
        row_start[i] = r;
        cursor[i] = r;
    }
    if (i == 0) row_start[N_NODES] = N_EDGES;
}

// scatter: CSR order (src, eid) pairs — 8B scattered per edge
__global__ void scatter_kernel(
    const int* __restrict__ src, const int* __restrict__ dst,
    int* __restrict__ cursor, int2* __restrict__ csr_se)
{
    int e = blockIdx.x * blockDim.x + threadIdx.x;
    if (e < N_EDGES) {
        int d   = dst[e];
        int pos = atomicAdd(&cursor[d], 1);
        csr_se[pos] = make_int2(src[e], e);
    }
}

// ---------------------------------------------------------------------------
// One wave per node, lane owns channels 2l,2l+1 (head = l>>4).
// 8-edge groups: lane L loads ea word (edge L>>3, word L&7) -> LDS bounce
// (issue-early / write-late), gathers xl per edge. Depth-2 pipeline.
// Softmax without running max; self-loop e-proj via linearity.
// ---------------------------------------------------------------------------
__global__ __launch_bounds__(256, 8) void node_kernel(
    const float* __restrict__ x, const unsigned short* __restrict__ xlb,
    const float* __restrict__ xr,
    const int* __restrict__ row_start, const int2* __restrict__ csr_se,
    const uint* __restrict__ ea_w,
    const float* __restrict__ We, const float* __restrict__ att,
    const float* __restrict__ bias, float* __restrict__ out)
{
    __shared__ uint ealds[4][128];   // per-wave: 2 bufs x 64 words
    int wid  = threadIdx.x >> 6;
    int lane = threadIdx.x & 63;
    int node = blockIdx.x * 4 + wid;
    if (node >= N_NODES) return;
    uint* my = ealds[wid];

    int c0 = 2 * lane, c1 = 2 * lane + 1;

    uint wpA[8], wpB[8];
    {
        const float4* wa = (const float4*)(We + (size_t)c0 * F_EDGE);
        const float4* wb = (const float4*)(We + (size_t)c1 * F_EDGE);
        #pragma unroll
        for (int q = 0; q < 4; ++q) {
            float4 va = wa[q], vb = wb[q];
            wpA[2*q]   = pack_bf2(va.x, va.y);
            wpA[2*q+1] = pack_bf2(va.z, va.w);
            wpB[2*q]   = pack_bf2(vb.x, vb.y);
            wpB[2*q+1] = pack_bf2(vb.z, vb.w);
        }
    }
    float attA = att[c0], attB = att[c1];
    float2 xrv = *(const float2*)(xr + (size_t)node * HC + c0);
    float xrA = xrv.x, xrB = xrv.y;

    int rs = row_start[node], re = row_start[node + 1];
    int deg = re - rs;

    const uint* xl32 = (const uint*)xlb;

    float d = 0.f, accA = 0.f, accB = 0.f;
    float eAs = 0.f, eBs = 0.f;

    auto edge_op = [&](const uint ea[8], uint g) {
        float eA = 0.f, eB = 0.f;
        #pragma unroll
        for (int k = 0; k < 8; ++k) {
            eA = dot2bf(ea[k], wpA[k], eA);
            eB = dot2bf(ea[k], wpB[k], eB);
        }
        eAs += eA; eBs += eB;
        float xlA = bf_lo(g), xlB = bf_hi(g);
        float sA = (xrA + eA) + xlA;
        float sB = (xrB + eB) + xlB;
        float aA = fmaxf(sA, 0.f) + NEG * fminf(sA, 0.f);
        float aB = fmaxf(sB, 0.f) + NEG * fminf(sB, 0.f);
        float p = aA * attA + aB * attB;
        p += __shfl_xor(p, 1);
        p += __shfl_xor(p, 2);
        p += __shfl_xor(p, 4);
        p += __shfl_xor(p, 8);
        float w = __expf(p);
        d += w;
        accA = fmaf(w, xlA, accA);
        accB = fmaf(w, xlB, accB);
    };

    int ngrp = deg >> 3;
    if (ngrp > 0) {
        int2 seA, seB;
        uint wA = 0, wB = 0;
        uint gA[8], gB[8];

        auto LOAD = [&](int jb, int2& se, uint& w, uint g[8]) {
            se = csr_se[jb + (lane >> 3)];
            w  = ea_w[(size_t)se.y * 8 + (lane & 7)];
            #pragma unroll
            for (int k = 0; k < 8; ++k) {
                int s = __shfl(se.x, 8 * k);
                g[k] = xl32[(size_t)s * 64 + lane];
            }
        };
        auto COMP = [&](int buf, const uint g[8]) {
            #pragma unroll
            for (int k = 0; k < 8; ++k) {
                const uint2* ep = (const uint2*)&my[buf * 64 + k * 8];
                uint2 q0 = ep[0], q1 = ep[1], q2 = ep[2], q3 = ep[3];
                uint ea[8] = {q0.x, q0.y, q1.x, q1.y, q2.x, q2.y, q3.x, q3.y};
                edge_op(ea, g[k]);
            }
        };

        LOAD(rs, seA, wA, gA);
        for (int gq = 0; gq < ngrp; gq += 2) {
            bool hasB = (gq + 1 < ngrp);
            if (hasB) LOAD(rs + 8 * (gq + 1), seB, wB, gB);
            my[lane] = wA;              // write-late into buf0
            COMP(0, gA);
            if (hasB) {
                if (gq + 2 < ngrp) LOAD(rs + 8 * (gq + 2), seA, wA, gA);
                my[64 + lane] = wB;     // buf1
                COMP(1, gB);
            }
        }
    }
    // tail edges (deg % 8)
    for (int j = rs + (ngrp << 3); j < re; ++j) {
        int2 se = csr_se[j];
        uint g = xl32[(size_t)se.x * 64 + lane];
        const uint4* ep = (const uint4*)(ea_w + (size_t)se.y * 8);
        uint4 a = ep[0], b = ep[1];
        uint ea[8] = {a.x, a.y, a.z, a.w, b.x, b.y, b.z, b.w};
        edge_op(ea, g);
    }

    // self-loop: e_proj = mean of per-edge e_proj (linearity of We)
    {
        float inv = 1.f / (float)(deg > 0 ? deg : 1);
        uint g = xl32[(size_t)node * 64 + lane];
        float xlA = bf_lo(g), xlB = bf_hi(g);
        float eA = eAs * inv, eB = eBs * inv;
        float sA = (xrA + eA) + xlA;
        float sB = (xrB + eB) + xlB;
        float aA = fmaxf(sA, 0.f) + NEG * fminf(sA, 0.f);
        float aB = fmaxf(sB, 0.f) + NEG * fminf(sB, 0.f);
        float p = aA * attA + aB * attB;
        p += __shfl_xor(p, 1);
        p += __shfl_xor(p, 2);
        p += __shfl_xor(p, 4);
        p += __shfl_xor(p, 8);
        float w = __expf(p);
        d += w;
        accA = fmaf(w, xlA, accA);
        accB = fmaf(w, xlB, accB);
    }

    float invd = 1.f / d;
    float oA = accA * invd + bias[c0];
    float oB = accB * invd + bias[c1];
    float2 xv = *(const float2*)(x + (size_t)node * HC + c0);
    float2 o;
    o.x = fmaxf(oA, 0.f) + xv.x;
    o.y = fmaxf(oB, 0.f) + xv.y;
    *(float2*)(out + (size_t)node * HC + c0) = o;
}

// ---------------------------------------------------------------------------
extern "C" void kernel_launch(void* const* d_in, const int* in_sizes, int n_in,
                              void* d_out, int out_size, void* d_ws, size_t ws_size,
                              hipStream_t stream)
{
    const float* x         = (const float*)d_in[0];
    const int*   ei        = (const int*)d_in[1];
    const float* edge_attr = (const float*)d_in[2];
    const float* Wl   = (const float*)d_in[5];
    const float* bl   = (const float*)d_in[6];
    const float* Wr   = (const float*)d_in[7];
    const float* br   = (const float*)d_in[8];
    const float* We   = (const float*)d_in[9];
    const float* att  = (const float*)d_in[10];
    const float* bias = (const float*)d_in[11];
    float* out = (float*)d_out;

    const int* src = ei;
    const int* dst = ei + N_EDGES;

    char* p = (char*)d_ws;
    auto alloc = [&](size_t bytes) {
        void* r = (void*)p;
        p += (bytes + 255) & ~(size_t)255;
        return r;
    };
    unsigned short* xlb = (unsigned short*)alloc((size_t)N_NODES * HC * sizeof(unsigned short));
    float* xr       = (float*)alloc((size_t)N_NODES * HC * sizeof(float));
    int* deg        = (int*)alloc((size_t)N_NODES * sizeof(int));
    int* row_start  = (int*)alloc((size_t)(N_NODES + 1) * sizeof(int));
    int* cursor     = (int*)alloc((size_t)N_NODES * sizeof(int));
    int2* csr_se    = (int2*)alloc((size_t)N_EDGES * sizeof(int2));
    uint4* ea_bf    = (uint4*)alloc((size_t)N_EDGES * 2 * sizeof(uint4));
    int* bsum       = (int*)alloc(256 * sizeof(int));
    int* boff       = (int*)alloc(256 * sizeof(int));

    hipMemsetAsync(deg, 0, (size_t)N_NODES * sizeof(int), stream);

    {
        int rblocks = (N_NODES + 63) / 64;     // 1563
        proj_kernel<<<rblocks * 4, 256, 0, stream>>>(x, Wl, bl, Wr, br, xlb, xr);
    }
    ea2bf_count_kernel<<<(N_EDGES + 255) / 256, 256, 0, stream>>>(edge_attr, dst, ea_bf, deg);
    scan1_kernel<<<NB_SCAN, 1024, 0, stream>>>(deg, row_start, bsum);
    scan2_kernel<<<1, 128, 0, stream>>>(bsum, boff);
    scan3_kernel<<<NB_SCAN, 1024, 0, stream>>>(row_start, boff, cursor);
    scatter_kernel<<<(N_EDGES + 255) / 256, 256, 0, stream>>>(src, dst, cursor, csr_se);
    node_kernel<<<(N_NODES + 3) / 4, 256, 0, stream>>>(
        x, xlb, xr, row_start, csr_se, (const uint*)ea_bf, We, att, bias, out);
}

// Round 5
// 656.430 us; speedup vs baseline: 1.1669x; 1.1669x over previous
//
#include <hip/hip_runtime.h>
#include <hip/hip_bf16.h>
#include <math.h>

#define N_NODES 100000
#define N_EDGES 1600000
#define F_IN 128
#define F_EDGE 16
#define HC 128   // HEADS*C = 4*32
#define NEG 0.2f
#define NB_SCAN 98   // ceil(N_NODES/1024)

typedef unsigned int uint;

__device__ __forceinline__ float bf_lo(uint u) { return __uint_as_float(u << 16); }
__device__ __forceinline__ float bf_hi(uint u) { return __uint_as_float(u & 0xffff0000u); }
__device__ __forceinline__ uint f2bfbits(float f) {
    union { __hip_bfloat16 h; unsigned short u; } cv;
    cv.h = __float2bfloat16(f);
    return (uint)cv.u;
}
__device__ __forceinline__ uint pack_bf2(float lo, float hi) {
    return f2bfbits(lo) | (f2bfbits(hi) << 16);
}

#if defined(__has_builtin)
#if __has_builtin(__builtin_amdgcn_fdot2_f32_bf16)
#define HAVE_DOT2_BF16 1
#endif
#endif

#ifdef HAVE_DOT2_BF16
typedef __attribute__((ext_vector_type(2))) __bf16 bf16x2_t;
__device__ __forceinline__ float dot2bf(uint a, uint b, float c) {
    return __builtin_amdgcn_fdot2_f32_bf16(
        __builtin_bit_cast(bf16x2_t, a), __builtin_bit_cast(bf16x2_t, b), c, false);
}
#else
__device__ __forceinline__ float dot2bf(uint a, uint b, float c) {
    return fmaf(bf_lo(a), bf_lo(b), fmaf(bf_hi(a), bf_hi(b), c));
}
#endif

// ---------------------------------------------------------------------------
// Projection with bf16 LDS tiles + dot2: xl = bf16(x@Wl^T+bl), xr = bf16(x@Wr^T+br)
// ---------------------------------------------------------------------------
__global__ __launch_bounds__(256) void proj_kernel(
    const float* __restrict__ x,
    const float* __restrict__ Wl, const float* __restrict__ bl,
    const float* __restrict__ Wr, const float* __restrict__ br,
    unsigned short* __restrict__ xlb, unsigned short* __restrict__ xrb)
{
    __shared__ uint2 xs[64 * 32];   // 16KB
    __shared__ uint2 ws[64 * 32];   // 16KB

    int bx = blockIdx.x;
    int rb = bx >> 2;
    int cb = bx & 3;
    int row0 = rb * 64;
    int col0 = (cb & 1) * 64;
    const float* W    = (cb < 2) ? Wl : Wr;
    const float* bias = (cb < 2) ? bl : br;
    unsigned short* outb = (cb < 2) ? xlb : xrb;

    int tid = threadIdx.x;

    #pragma unroll
    for (int i = 0; i < 8; ++i) {
        int f  = tid + 256 * i;
        int r  = f >> 5;
        int u  = f & 31;
        int gr = row0 + r;
        float4 v = make_float4(0.f, 0.f, 0.f, 0.f);
        if (gr < N_NODES) v = ((const float4*)(x + (size_t)gr * F_IN))[u];
        uint2 pv; pv.x = pack_bf2(v.x, v.y); pv.y = pack_bf2(v.z, v.w);
        xs[r * 32 + (u ^ (r & 31))] = pv;
    }
    #pragma unroll
    for (int i = 0; i < 8; ++i) {
        int f  = tid + 256 * i;
        int r  = f >> 5;
        int u  = f & 31;
        float4 v = ((const float4*)(W + (size_t)(col0 + r) * F_IN))[u];
        uint2 pv; pv.x = pack_bf2(v.x, v.y); pv.y = pack_bf2(v.z, v.w);
        ws[r * 32 + (u ^ (r & 31))] = pv;
    }
    __syncthreads();

    int tx = tid & 15, ty = tid >> 4;
    float acc[4][4];
    #pragma unroll
    for (int i = 0; i < 4; ++i)
        #pragma unroll
        for (int j = 0; j < 4; ++j) acc[i][j] = 0.f;

    for (int u = 0; u < 32; ++u) {
        uint2 a[4], b[4];
        #pragma unroll
        for (int i = 0; i < 4; ++i) {
            int r = ty + 16 * i;
            a[i] = xs[r * 32 + (u ^ (r & 31))];
        }
        #pragma unroll
        for (int j = 0; j < 4; ++j) {
            int r = tx + 16 * j;
            b[j] = ws[r * 32 + (u ^ (r & 31))];
        }
        #pragma unroll
        for (int i = 0; i < 4; ++i)
            #pragma unroll
            for (int j = 0; j < 4; ++j) {
                acc[i][j] = dot2bf(a[i].x, b[j].x, acc[i][j]);
                acc[i][j] = dot2bf(a[i].y, b[j].y, acc[i][j]);
            }
    }

    #pragma unroll
    for (int i = 0; i < 4; ++i) {
        int gr = row0 + ty + 16 * i;
        if (gr >= N_NODES) continue;
        #pragma unroll
        for (int j = 0; j < 4; ++j) {
            int c = col0 + tx + 16 * j;
            float v = acc[i][j] + bias[c];
            outb[(size_t)gr * HC + c] = (unsigned short)f2bfbits(v);
        }
    }
}

// ---------------------------------------------------------------------------
__global__ void count_kernel(const int* __restrict__ dst, int* __restrict__ deg)
{
    int e = blockIdx.x * blockDim.x + threadIdx.x;
    if (e < N_EDGES) atomicAdd(&deg[dst[e]], 1);
}

// 3-phase scan
__global__ __launch_bounds__(1024) void scan1_kernel(
    const int* __restrict__ deg, int* __restrict__ row_start, int* __restrict__ bsum)
{
    __shared__ int sm[1024];
    int t = threadIdx.x;
    int i = blockIdx.x * 1024 + t;
    int v = (i < N_NODES) ? deg[i] : 0;
    sm[t] = v;
    __syncthreads();
    for (int off = 1; off < 1024; off <<= 1) {
        int o = (t >= off) ? sm[t - off] : 0;
        __syncthreads();
        sm[t] += o;
        __syncthreads();
    }
    if (i < N_NODES) row_start[i] = sm[t] - v;
    if (t == 1023) bsum[blockIdx.x] = sm[1023];
}

__global__ __launch_bounds__(128) void scan2_kernel(
    const int* __restrict__ bsum, int* __restrict__ boff)
{
    __shared__ int sm[128];
    int t = threadIdx.x;
    int v = (t < NB_SCAN) ? bsum[t] : 0;
    sm[t] = v;
    __syncthreads();
    for (int off = 1; off < 128; off <<= 1) {
        int o = (t >= off) ? sm[t - off] : 0;
        __syncthreads();
        sm[t] += o;
        __syncthreads();
    }
    if (t < NB_SCAN) boff[t] = sm[t] - v;
}

__global__ __launch_bounds__(1024) void scan3_kernel(
    int* __restrict__ row_start, const int* __restrict__ boff, int* __restrict__ cursor)
{
    int i = blockIdx.x * 1024 + threadIdx.x;
    if (i < N_NODES) {
        int r = row_start[i] + boff[blockIdx.x];
        row_start[i] = r;
        cursor[i] = r;
    }
    if (i == 0) row_start[N_NODES] = N_EDGES;
}

// scatter: CSR-ordered src (4B) + CSR-ordered bf16 edge_attr (32B) per edge
__global__ void scatter_kernel(
    const int* __restrict__ src, const int* __restrict__ dst,
    const float* __restrict__ edge_attr,
    int* __restrict__ cursor, int* __restrict__ csr_src, uint4* __restrict__ csr_ea)
{
    int e = blockIdx.x * blockDim.x + threadIdx.x;
    if (e < N_EDGES) {
        int d   = dst[e];
        int pos = atomicAdd(&cursor[d], 1);
        csr_src[pos] = src[e];
        const float4* ep = (const float4*)(edge_attr + (size_t)e * F_EDGE);
        float4 t0 = ep[0], t1 = ep[1], t2 = ep[2], t3 = ep[3];
        uint4 a, b;
        a.x = pack_bf2(t0.x, t0.y);  a.y = pack_bf2(t0.z, t0.w);
        a.z = pack_bf2(t1.x, t1.y);  a.w = pack_bf2(t1.z, t1.w);
        b.x = pack_bf2(t2.x, t2.y);  b.y = pack_bf2(t2.z, t2.w);
        b.z = pack_bf2(t3.x, t3.y);  b.w = pack_bf2(t3.z, t3.w);
        csr_ea[2 * (size_t)pos]     = a;
        csr_ea[2 * (size_t)pos + 1] = b;
    }
}

// ---------------------------------------------------------------------------
// One wave per node, lane owns channels 2l,2l+1 (head = l>>4).
// 8-edge groups: ea read is 256B CONTIGUOUS (CSR order), lane L loads word L
// -> LDS bounce; xl gathered per edge. Depth-2 group pipeline.
// Softmax without running max; self-loop e-proj via linearity.
// ---------------------------------------------------------------------------
__global__ __launch_bounds__(256, 8) void node_kernel(
    const float* __restrict__ x, const unsigned short* __restrict__ xlb,
    const unsigned short* __restrict__ xrb,
    const int* __restrict__ row_start, const int* __restrict__ csr_src,
    const uint* __restrict__ ea_w,
    const float* __restrict__ We, const float* __restrict__ att,
    const float* __restrict__ bias, float* __restrict__ out)
{
    __shared__ uint ealds[4][128];   // per-wave: 2 bufs x 64 words
    int wid  = threadIdx.x >> 6;
    int lane = threadIdx.x & 63;
    int node = blockIdx.x * 4 + wid;
    if (node >= N_NODES) return;
    uint* my = ealds[wid];

    int c0 = 2 * lane, c1 = 2 * lane + 1;

    uint wpA[8], wpB[8];
    {
        const float4* wa = (const float4*)(We + (size_t)c0 * F_EDGE);
        const float4* wb = (const float4*)(We + (size_t)c1 * F_EDGE);
        #pragma unroll
        for (int q = 0; q < 4; ++q) {
            float4 va = wa[q], vb = wb[q];
            wpA[2*q]   = pack_bf2(va.x, va.y);
            wpA[2*q+1] = pack_bf2(va.z, va.w);
            wpB[2*q]   = pack_bf2(vb.x, vb.y);
            wpB[2*q+1] = pack_bf2(vb.z, vb.w);
        }
    }
    float attA = att[c0], attB = att[c1];
    uint xru = ((const uint*)xrb)[(size_t)node * 64 + lane];
    float xrA = bf_lo(xru), xrB = bf_hi(xru);

    int rs = row_start[node], re = row_start[node + 1];
    int deg = re - rs;

    const uint* xl32 = (const uint*)xlb;

    float d = 0.f, accA = 0.f, accB = 0.f;
    float eAs = 0.f, eBs = 0.f;

    auto edge_op = [&](const uint ea[8], uint g) {
        float eA = 0.f, eB = 0.f;
        #pragma unroll
        for (int k = 0; k < 8; ++k) {
            eA = dot2bf(ea[k], wpA[k], eA);
            eB = dot2bf(ea[k], wpB[k], eB);
        }
        eAs += eA; eBs += eB;
        float xlA = bf_lo(g), xlB = bf_hi(g);
        float sA = (xrA + eA) + xlA;
        float sB = (xrB + eB) + xlB;
        float aA = fmaxf(sA, 0.f) + NEG * fminf(sA, 0.f);
        float aB = fmaxf(sB, 0.f) + NEG * fminf(sB, 0.f);
        float p = aA * attA + aB * attB;
        p += __shfl_xor(p, 1);
        p += __shfl_xor(p, 2);
        p += __shfl_xor(p, 4);
        p += __shfl_xor(p, 8);
        float w = __expf(p);
        d += w;
        accA = fmaf(w, xlA, accA);
        accB = fmaf(w, xlB, accB);
    };

    int ngrp = deg >> 3;
    if (ngrp > 0) {
        int sA8, sB8;
        uint wA = 0, wB = 0;
        uint gA[8], gB[8];

        auto LOAD = [&](int jb, int& s8, uint& w, uint g[8]) {
            s8 = csr_src[jb + (lane >> 3)];              // 8 srcs, broadcast in clusters
            w  = ea_w[(size_t)jb * 8 + lane];            // 256B contiguous
            #pragma unroll
            for (int k = 0; k < 8; ++k) {
                int s = __shfl(s8, 8 * k);
                g[k] = xl32[(size_t)s * 64 + lane];
            }
        };
        auto COMP = [&](int buf, const uint g[8]) {
            #pragma unroll
            for (int k = 0; k < 8; ++k) {
                const uint2* ep = (const uint2*)&my[buf * 64 + k * 8];
                uint2 q0 = ep[0], q1 = ep[1], q2 = ep[2], q3 = ep[3];
                uint ea[8] = {q0.x, q0.y, q1.x, q1.y, q2.x, q2.y, q3.x, q3.y};
                edge_op(ea, g[k]);
            }
        };

        LOAD(rs, sA8, wA, gA);
        for (int gq = 0; gq < ngrp; gq += 2) {
            bool hasB = (gq + 1 < ngrp);
            if (hasB) LOAD(rs + 8 * (gq + 1), sB8, wB, gB);
            my[lane] = wA;              // buf0
            COMP(0, gA);
            if (hasB) {
                if (gq + 2 < ngrp) LOAD(rs + 8 * (gq + 2), sA8, wA, gA);
                my[64 + lane] = wB;     // buf1
                COMP(1, gB);
            }
        }
    }
    // tail edges (deg % 8)
    for (int j = rs + (ngrp << 3); j < re; ++j) {
        int s = csr_src[j];
        uint g = xl32[(size_t)s * 64 + lane];
        const uint4* ep = (const uint4*)(ea_w + (size_t)j * 8);
        uint4 a = ep[0], b = ep[1];
        uint ea[8] = {a.x, a.y, a.z, a.w, b.x, b.y, b.z, b.w};
        edge_op(ea, g);
    }

    // self-loop: e_proj = mean of per-edge e_proj (linearity of We)
    {
        float inv = 1.f / (float)(deg > 0 ? deg : 1);
        uint g = xl32[(size_t)node * 64 + lane];
        float xlA = bf_lo(g), xlB = bf_hi(g);
        float eA = eAs * inv, eB = eBs * inv;
        float sA = (xrA + eA) + xlA;
        float sB = (xrB + eB) + xlB;
        float aA = fmaxf(sA, 0.f) + NEG * fminf(sA, 0.f);
        float aB = fmaxf(sB, 0.f) + NEG * fminf(sB, 0.f);
        float p = aA * attA + aB * attB;
        p += __shfl_xor(p, 1);
        p += __shfl_xor(p, 2);
        p += __shfl_xor(p, 4);
        p += __shfl_xor(p, 8);
        float w = __expf(p);
        d += w;
        accA = fmaf(w, xlA, accA);
        accB = fmaf(w, xlB, accB);
    }

    float invd = 1.f / d;
    float oA = accA * invd + bias[c0];
    float oB = accB * invd + bias[c1];
    float2 xv = *(const float2*)(x + (size_t)node * HC + c0);
    float2 o;
    o.x = fmaxf(oA, 0.f) + xv.x;
    o.y = fmaxf(oB, 0.f) + xv.y;
    *(float2*)(out + (size_t)node * HC + c0) = o;
}

// ---------------------------------------------------------------------------
extern "C" void kernel_launch(void* const* d_in, const int* in_sizes, int n_in,
                              void* d_out, int out_size, void* d_ws, size_t ws_size,
                              hipStream_t stream)
{
    const float* x         = (const float*)d_in[0];
    const int*   ei        = (const int*)d_in[1];
    const float* edge_attr = (const float*)d_in[2];
    const float* Wl   = (const float*)d_in[5];
    const float* bl   = (const float*)d_in[6];
    const float* Wr   = (const float*)d_in[7];
    const float* br   = (const float*)d_in[8];
    const float* We   = (const float*)d_in[9];
    const float* att  = (const float*)d_in[10];
    const float* bias = (const float*)d_in[11];
    float* out = (float*)d_out;

    const int* src = ei;
    const int* dst = ei + N_EDGES;

    char* p = (char*)d_ws;
    auto alloc = [&](size_t bytes) {
        void* r = (void*)p;
        p += (bytes + 255) & ~(size_t)255;
        return r;
    };
    unsigned short* xlb = (unsigned short*)alloc((size_t)N_NODES * HC * sizeof(unsigned short));
    unsigned short* xrb = (unsigned short*)alloc((size_t)N_NODES * HC * sizeof(unsigned short));
    int* deg        = (int*)alloc((size_t)N_NODES * sizeof(int));
    int* row_start  = (int*)alloc((size_t)(N_NODES + 1) * sizeof(int));
    int* cursor     = (int*)alloc((size_t)N_NODES * sizeof(int));
    int* csr_src    = (int*)alloc((size_t)N_EDGES * sizeof(int));
    uint4* csr_ea   = (uint4*)alloc((size_t)N_EDGES * 2 * sizeof(uint4));
    int* bsum       = (int*)alloc(256 * sizeof(int));
    int* boff       = (int*)alloc(256 * sizeof(int));

    hipMemsetAsync(deg, 0, (size_t)N_NODES * sizeof(int), stream);

    {
        int rblocks = (N_NODES + 63) / 64;     // 1563
        proj_kernel<<<rblocks * 4, 256, 0, stream>>>(x, Wl, bl, Wr, br, xlb, xrb);
    }
    count_kernel<<<(N_EDGES + 255) / 256, 256, 0, stream>>>(dst, deg);
    scan1_kernel<<<NB_SCAN, 1024, 0, stream>>>(deg, row_start, bsum);
    scan2_kernel<<<1, 128, 0, stream>>>(bsum, boff);
    scan3_kernel<<<NB_SCAN, 1024, 0, stream>>>(row_start, boff, cursor);
    scatter_kernel<<<(N_EDGES + 255) / 256, 256, 0, stream>>>(src, dst, edge_attr, cursor, csr_src, csr_ea);
    node_kernel<<<(N_NODES + 3) / 4, 256, 0, stream>>>(
        x, xlb, xrb, row_start, csr_src, (const uint*)csr_ea, We, att, bias, out);
}

// Round 6
// 532.996 us; speedup vs baseline: 1.4371x; 1.2316x over previous
//
#include <hip/hip_runtime.h>
#include <hip/hip_bf16.h>
#include <math.h>

#define N_NODES 100000
#define N_EDGES 1600000
#define F_IN 128
#define F_EDGE 16
#define HC 128   // HEADS*C = 4*32
#define NEG 0.2f
#define NB_SCAN 98   // ceil(N_NODES/1024)

typedef unsigned int uint;

__device__ __forceinline__ float bf_lo(uint u) { return __uint_as_float(u << 16); }
__device__ __forceinline__ float bf_hi(uint u) { return __uint_as_float(u & 0xffff0000u); }
__device__ __forceinline__ uint f2bfbits(float f) {
    union { __hip_bfloat16 h; unsigned short u; } cv;
    cv.h = __float2bfloat16(f);
    return (uint)cv.u;
}
__device__ __forceinline__ uint pack_bf2(float lo, float hi) {
    return f2bfbits(lo) | (f2bfbits(hi) << 16);
}

#if defined(__has_builtin)
#if __has_builtin(__builtin_amdgcn_fdot2_f32_bf16)
#define HAVE_DOT2_BF16 1
#endif
#endif

#ifdef HAVE_DOT2_BF16
typedef __attribute__((ext_vector_type(2))) __bf16 bf16x2_t;
__device__ __forceinline__ float dot2bf(uint a, uint b, float c) {
    return __builtin_amdgcn_fdot2_f32_bf16(
        __builtin_bit_cast(bf16x2_t, a), __builtin_bit_cast(bf16x2_t, b), c, false);
}
#else
__device__ __forceinline__ float dot2bf(uint a, uint b, float c) {
    return fmaf(bf_lo(a), bf_lo(b), fmaf(bf_hi(a), bf_hi(b), c));
}
#endif

// ---------------------------------------------------------------------------
// Projection with bf16 LDS tiles + dot2: xl = bf16(x@Wl^T+bl), xr = bf16(x@Wr^T+br)
// ---------------------------------------------------------------------------
__global__ __launch_bounds__(256) void proj_kernel(
    const float* __restrict__ x,
    const float* __restrict__ Wl, const float* __restrict__ bl,
    const float* __restrict__ Wr, const float* __restrict__ br,
    unsigned short* __restrict__ xlb, unsigned short* __restrict__ xrb)
{
    __shared__ uint2 xs[64 * 32];   // 16KB
    __shared__ uint2 ws[64 * 32];   // 16KB

    int bx = blockIdx.x;
    int rb = bx >> 2;
    int cb = bx & 3;
    int row0 = rb * 64;
    int col0 = (cb & 1) * 64;
    const float* W    = (cb < 2) ? Wl : Wr;
    const float* bias = (cb < 2) ? bl : br;
    unsigned short* outb = (cb < 2) ? xlb : xrb;

    int tid = threadIdx.x;

    #pragma unroll
    for (int i = 0; i < 8; ++i) {
        int f  = tid + 256 * i;
        int r  = f >> 5;
        int u  = f & 31;
        int gr = row0 + r;
        float4 v = make_float4(0.f, 0.f, 0.f, 0.f);
        if (gr < N_NODES) v = ((const float4*)(x + (size_t)gr * F_IN))[u];
        uint2 pv; pv.x = pack_bf2(v.x, v.y); pv.y = pack_bf2(v.z, v.w);
        xs[r * 32 + (u ^ (r & 31))] = pv;
    }
    #pragma unroll
    for (int i = 0; i < 8; ++i) {
        int f  = tid + 256 * i;
        int r  = f >> 5;
        int u  = f & 31;
        float4 v = ((const float4*)(W + (size_t)(col0 + r) * F_IN))[u];
        uint2 pv; pv.x = pack_bf2(v.x, v.y); pv.y = pack_bf2(v.z, v.w);
        ws[r * 32 + (u ^ (r & 31))] = pv;
    }
    __syncthreads();

    int tx = tid & 15, ty = tid >> 4;
    float acc[4][4];
    #pragma unroll
    for (int i = 0; i < 4; ++i)
        #pragma unroll
        for (int j = 0; j < 4; ++j) acc[i][j] = 0.f;

    for (int u = 0; u < 32; ++u) {
        uint2 a[4], b[4];
        #pragma unroll
        for (int i = 0; i < 4; ++i) {
            int r = ty + 16 * i;
            a[i] = xs[r * 32 + (u ^ (r & 31))];
        }
        #pragma unroll
        for (int j = 0; j < 4; ++j) {
            int r = tx + 16 * j;
            b[j] = ws[r * 32 + (u ^ (r & 31))];
        }
        #pragma unroll
        for (int i = 0; i < 4; ++i)
            #pragma unroll
            for (int j = 0; j < 4; ++j) {
                acc[i][j] = dot2bf(a[i].x, b[j].x, acc[i][j]);
                acc[i][j] = dot2bf(a[i].y, b[j].y, acc[i][j]);
            }
    }

    #pragma unroll
    for (int i = 0; i < 4; ++i) {
        int gr = row0 + ty + 16 * i;
        if (gr >= N_NODES) continue;
        #pragma unroll
        for (int j = 0; j < 4; ++j) {
            int c = col0 + tx + 16 * j;
            float v = acc[i][j] + bias[c];
            outb[(size_t)gr * HC + c] = (unsigned short)f2bfbits(v);
        }
    }
}

// ---------------------------------------------------------------------------
__global__ void count_kernel(const int* __restrict__ dst, int* __restrict__ deg)
{
    int e = blockIdx.x * blockDim.x + threadIdx.x;
    if (e < N_EDGES) atomicAdd(&deg[dst[e]], 1);
}

// 3-phase scan
__global__ __launch_bounds__(1024) void scan1_kernel(
    const int* __restrict__ deg, int* __restrict__ row_start, int* __restrict__ bsum)
{
    __shared__ int sm[1024];
    int t = threadIdx.x;
    int i = blockIdx.x * 1024 + t;
    int v = (i < N_NODES) ? deg[i] : 0;
    sm[t] = v;
    __syncthreads();
    for (int off = 1; off < 1024; off <<= 1) {
        int o = (t >= off) ? sm[t - off] : 0;
        __syncthreads();
        sm[t] += o;
        __syncthreads();
    }
    if (i < N_NODES) row_start[i] = sm[t] - v;
    if (t == 1023) bsum[blockIdx.x] = sm[1023];
}

__global__ __launch_bounds__(128) void scan2_kernel(
    const int* __restrict__ bsum, int* __restrict__ boff)
{
    __shared__ int sm[128];
    int t = threadIdx.x;
    int v = (t < NB_SCAN) ? bsum[t] : 0;
    sm[t] = v;
    __syncthreads();
    for (int off = 1; off < 128; off <<= 1) {
        int o = (t >= off) ? sm[t - off] : 0;
        __syncthreads();
        sm[t] += o;
        __syncthreads();
    }
    if (t < NB_SCAN) boff[t] = sm[t] - v;
}

__global__ __launch_bounds__(1024) void scan3_kernel(
    int* __restrict__ row_start, const int* __restrict__ boff, int* __restrict__ cursor)
{
    int i = blockIdx.x * 1024 + threadIdx.x;
    if (i < N_NODES) {
        int r = row_start[i] + boff[blockIdx.x];
        row_start[i] = r;
        cursor[i] = r;
    }
    if (i == 0) row_start[N_NODES] = N_EDGES;
}

// scatter: CSR-ordered src (4B) + CSR-ordered bf16 edge_attr (32B) per edge
__global__ void scatter_kernel(
    const int* __restrict__ src, const int* __restrict__ dst,
    const float* __restrict__ edge_attr,
    int* __restrict__ cursor, int* __restrict__ csr_src, uint4* __restrict__ csr_ea)
{
    int e = blockIdx.x * blockDim.x + threadIdx.x;
    if (e < N_EDGES) {
        int d   = dst[e];
        int pos = atomicAdd(&cursor[d], 1);
        csr_src[pos] = src[e];
        const float4* ep = (const float4*)(edge_attr + (size_t)e * F_EDGE);
        float4 t0 = ep[0], t1 = ep[1], t2 = ep[2], t3 = ep[3];
        uint4 a, b;
        a.x = pack_bf2(t0.x, t0.y);  a.y = pack_bf2(t0.z, t0.w);
        a.z = pack_bf2(t1.x, t1.y);  a.w = pack_bf2(t1.z, t1.w);
        b.x = pack_bf2(t2.x, t2.y);  b.y = pack_bf2(t2.z, t2.w);
        b.z = pack_bf2(t3.x, t3.y);  b.w = pack_bf2(t3.z, t3.w);
        csr_ea[2 * (size_t)pos]     = a;
        csr_ea[2 * (size_t)pos + 1] = b;
    }
}

// ---------------------------------------------------------------------------
// One wave per node, lane owns channels 2l,2l+1 (head = l>>4).
// 8-edge groups: ea read is 256B contiguous (CSR order), LDS bounce;
// xl gathered per edge. Depth-2 group pipeline. Softmax without running max.
// __launch_bounds__(256,4): 128-VGPR budget -> NO scratch spills (R5's
// (256,8) forced 32 VGPRs and spilled ~730MB/dispatch to HBM).
// ---------------------------------------------------------------------------
__global__ __launch_bounds__(256, 4) void node_kernel(
    const float* __restrict__ x, const unsigned short* __restrict__ xlb,
    const unsigned short* __restrict__ xrb,
    const int* __restrict__ row_start, const int* __restrict__ csr_src,
    const uint* __restrict__ ea_w,
    const float* __restrict__ We, const float* __restrict__ att,
    const float* __restrict__ bias, float* __restrict__ out)
{
    __shared__ uint ealds[4][128];   // per-wave: 2 bufs x 64 words
    int wid  = threadIdx.x >> 6;
    int lane = threadIdx.x & 63;
    int node = blockIdx.x * 4 + wid;
    if (node >= N_NODES) return;
    uint* my = ealds[wid];

    int c0 = 2 * lane, c1 = 2 * lane + 1;

    uint wpA[8], wpB[8];
    {
        const float4* wa = (const float4*)(We + (size_t)c0 * F_EDGE);
        const float4* wb = (const float4*)(We + (size_t)c1 * F_EDGE);
        #pragma unroll
        for (int q = 0; q < 4; ++q) {
            float4 va = wa[q], vb = wb[q];
            wpA[2*q]   = pack_bf2(va.x, va.y);
            wpA[2*q+1] = pack_bf2(va.z, va.w);
            wpB[2*q]   = pack_bf2(vb.x, vb.y);
            wpB[2*q+1] = pack_bf2(vb.z, vb.w);
        }
    }
    float attA = att[c0], attB = att[c1];
    uint xru = ((const uint*)xrb)[(size_t)node * 64 + lane];
    float xrA = bf_lo(xru), xrB = bf_hi(xru);

    int rs = row_start[node], re = row_start[node + 1];
    int deg = re - rs;

    const uint* xl32 = (const uint*)xlb;

    float d = 0.f, accA = 0.f, accB = 0.f;
    float eAs = 0.f, eBs = 0.f;

    auto edge_op = [&](const uint ea[8], uint g) {
        float eA = 0.f, eB = 0.f;
        #pragma unroll
        for (int k = 0; k < 8; ++k) {
            eA = dot2bf(ea[k], wpA[k], eA);
            eB = dot2bf(ea[k], wpB[k], eB);
        }
        eAs += eA; eBs += eB;
        float xlA = bf_lo(g), xlB = bf_hi(g);
        float sA = (xrA + eA) + xlA;
        float sB = (xrB + eB) + xlB;
        float aA = fmaxf(sA, 0.f) + NEG * fminf(sA, 0.f);
        float aB = fmaxf(sB, 0.f) + NEG * fminf(sB, 0.f);
        float p = aA * attA + aB * attB;
        p += __shfl_xor(p, 1);
        p += __shfl_xor(p, 2);
        p += __shfl_xor(p, 4);
        p += __shfl_xor(p, 8);
        float w = __expf(p);
        d += w;
        accA = fmaf(w, xlA, accA);
        accB = fmaf(w, xlB, accB);
    };

    int ngrp = deg >> 3;
    if (ngrp > 0) {
        int sA8, sB8;
        uint wA = 0, wB = 0;
        uint gA[8], gB[8];

        auto LOAD = [&](int jb, int& s8, uint& w, uint g[8]) {
            s8 = csr_src[jb + (lane >> 3)];              // 8 srcs, broadcast in clusters
            w  = ea_w[(size_t)jb * 8 + lane];            // 256B contiguous
            #pragma unroll
            for (int k = 0; k < 8; ++k) {
                int s = __shfl(s8, 8 * k);
                g[k] = xl32[(size_t)s * 64 + lane];
            }
        };
        auto COMP = [&](int buf, const uint g[8]) {
            #pragma unroll
            for (int k = 0; k < 8; ++k) {
                const uint2* ep = (const uint2*)&my[buf * 64 + k * 8];
                uint2 q0 = ep[0], q1 = ep[1], q2 = ep[2], q3 = ep[3];
                uint ea[8] = {q0.x, q0.y, q1.x, q1.y, q2.x, q2.y, q3.x, q3.y};
                edge_op(ea, g[k]);
            }
        };

        LOAD(rs, sA8, wA, gA);
        for (int gq = 0; gq < ngrp; gq += 2) {
            bool hasB = (gq + 1 < ngrp);
            if (hasB) LOAD(rs + 8 * (gq + 1), sB8, wB, gB);
            my[lane] = wA;              // buf0
            COMP(0, gA);
            if (hasB) {
                if (gq + 2 < ngrp) LOAD(rs + 8 * (gq + 2), sA8, wA, gA);
                my[64 + lane] = wB;     // buf1
                COMP(1, gB);
            }
        }
    }
    // tail edges (deg % 8)
    for (int j = rs + (ngrp << 3); j < re; ++j) {
        int s = csr_src[j];
        uint g = xl32[(size_t)s * 64 + lane];
        const uint4* ep = (const uint4*)(ea_w + (size_t)j * 8);
        uint4 a = ep[0], b = ep[1];
        uint ea[8] = {a.x, a.y, a.z, a.w, b.x, b.y, b.z, b.w};
        edge_op(ea, g);
    }

    // self-loop: e_proj = mean of per-edge e_proj (linearity of We)
    {
        float inv = 1.f / (float)(deg > 0 ? deg : 1);
        uint g = xl32[(size_t)node * 64 + lane];
        float xlA = bf_lo(g), xlB = bf_hi(g);
        float eA = eAs * inv, eB = eBs * inv;
        float sA = (xrA + eA) + xlA;
        float sB = (xrB + eB) + xlB;
        float aA = fmaxf(sA, 0.f) + NEG * fminf(sA, 0.f);
        float aB = fmaxf(sB, 0.f) + NEG * fminf(sB, 0.f);
        float p = aA * attA + aB * attB;
        p += __shfl_xor(p, 1);
        p += __shfl_xor(p, 2);
        p += __shfl_xor(p, 4);
        p += __shfl_xor(p, 8);
        float w = __expf(p);
        d += w;
        accA = fmaf(w, xlA, accA);
        accB = fmaf(w, xlB, accB);
    }

    float invd = 1.f / d;
    float oA = accA * invd + bias[c0];
    float oB = accB * invd + bias[c1];
    float2 xv = *(const float2*)(x + (size_t)node * HC + c0);
    float2 o;
    o.x = fmaxf(oA, 0.f) + xv.x;
    o.y = fmaxf(oB, 0.f) + xv.y;
    *(float2*)(out + (size_t)node * HC + c0) = o;
}

// ---------------------------------------------------------------------------
extern "C" void kernel_launch(void* const* d_in, const int* in_sizes, int n_in,
                              void* d_out, int out_size, void* d_ws, size_t ws_size,
                              hipStream_t stream)
{
    const float* x         = (const float*)d_in[0];
    const int*   ei        = (const int*)d_in[1];
    const float* edge_attr = (const float*)d_in[2];
    const float* Wl   = (const float*)d_in[5];
    const float* bl   = (const float*)d_in[6];
    const float* Wr   = (const float*)d_in[7];
    const float* br   = (const float*)d_in[8];
    const float* We   = (const float*)d_in[9];
    const float* att  = (const float*)d_in[10];
    const float* bias = (const float*)d_in[11];
    float* out = (float*)d_out;

    const int* src = ei;
    const int* dst = ei + N_EDGES;

    char* p = (char*)d_ws;
    auto alloc = [&](size_t bytes) {
        void* r = (void*)p;
        p += (bytes + 255) & ~(size_t)255;
        return r;
    };
    unsigned short* xlb = (unsigned short*)alloc((size_t)N_NODES * HC * sizeof(unsigned short));
    unsigned short* xrb = (unsigned short*)alloc((size_t)N_NODES * HC * sizeof(unsigned short));
    int* deg        = (int*)alloc((size_t)N_NODES * sizeof(int));
    int* row_start  = (int*)alloc((size_t)(N_NODES + 1) * sizeof(int));
    int* cursor     = (int*)alloc((size_t)N_NODES * sizeof(int));
    int* csr_src    = (int*)alloc((size_t)N_EDGES * sizeof(int));
    uint4* csr_ea   = (uint4*)alloc((size_t)N_EDGES * 2 * sizeof(uint4));
    int* bsum       = (int*)alloc(256 * sizeof(int));
    int* boff       = (int*)alloc(256 * sizeof(int));

    hipMemsetAsync(deg, 0, (size_t)N_NODES * sizeof(int), stream);

    {
        int rblocks = (N_NODES + 63) / 64;     // 1563
        proj_kernel<<<rblocks * 4, 256, 0, stream>>>(x, Wl, bl, Wr, br, xlb, xrb);
    }
    count_kernel<<<(N_EDGES + 255) / 256, 256, 0, stream>>>(dst, deg);
    scan1_kernel<<<NB_SCAN, 1024, 0, stream>>>(deg, row_start, bsum);
    scan2_kernel<<<1, 128, 0, stream>>>(bsum, boff);
    scan3_kernel<<<NB_SCAN, 1024, 0, stream>>>(row_start, boff, cursor);
    scatter_kernel<<<(N_EDGES + 255) / 256, 256, 0, stream>>>(src, dst, edge_attr, cursor, csr_src, csr_ea);
    node_kernel<<<(N_NODES + 3) / 4, 256, 0, stream>>>(
        x, xlb, xrb, row_start, csr_src, (const uint*)csr_ea, We, att, bias, out);
}